// Round 3
// baseline (181.391 us; speedup 1.0000x reference)
//
#include <hip/hip_runtime.h>
#include <hip/hip_bf16.h>

// MFMA fragment types (cdna_hip_programming.md §3)
typedef __attribute__((ext_vector_type(8))) short bf16x8;
typedef __attribute__((ext_vector_type(4))) float f32x4;

#define BATCH 64
#define SEQ   128
#define EMB   256
#define ENC   256
#define NIN   64
#define NSL   128

static __device__ __forceinline__ bf16x8 cvt8(const float4 lo, const float4 hi) {
    union { bf16x8 v; __hip_bfloat16 h[8]; } u;
    u.h[0] = __float2bfloat16(lo.x); u.h[1] = __float2bfloat16(lo.y);
    u.h[2] = __float2bfloat16(lo.z); u.h[3] = __float2bfloat16(lo.w);
    u.h[4] = __float2bfloat16(hi.x); u.h[5] = __float2bfloat16(hi.y);
    u.h[6] = __float2bfloat16(hi.z); u.h[7] = __float2bfloat16(hi.w);
    return u.v;
}

// ---------------------------------------------------------------------------
// Kernel 1: blocks 0..255 transpose+convert weights into ws (fp32 -> bf16);
//           blocks 256..319 run the whole doc path in fp32.
// ---------------------------------------------------------------------------
__global__ __launch_bounds__(256) void prep_doc_kernel(
    const int*   __restrict__ token_ids,
    const float* __restrict__ emb_table,
    const float* __restrict__ doc_enc_W,
    const float* __restrict__ doc_enc_b,
    const float* __restrict__ doc_dec_W,
    const float* __restrict__ doc_dec_b,
    const float* __restrict__ slot_enc_W,
    const float* __restrict__ slot_dec_W,
    __hip_bfloat16* __restrict__ W1T,     // [256][256] = bf16(slot_enc_W^T)
    __hip_bfloat16* __restrict__ W2aT,    // [128][256] = bf16(slot_dec_W[0:256]^T)
    float* __restrict__ out_intent)       // fp32 [64][64]
{
    __shared__ __align__(16) float red[4][256];
    __shared__ float sent[ENC];
    __shared__ float senc[ENC];
    const int blk = blockIdx.x;
    const int t   = threadIdx.x;

    if (blk < 256) {
        // Coalesced fp32 read, scattered 2B bf16 write (tiny, L2-resident).
        const int idx = blk * 256 + t;            // 0 .. 65535
        const int k = idx >> 8;                   // source row
        const int n = idx & 255;                  // source col
        W1T[n * 256 + k] = __float2bfloat16(slot_enc_W[idx]);
        if (idx < 256 * 128) {                    // first 256 rows of slot_dec_W
            const int k2 = idx >> 7;
            const int n2 = idx & 127;
            W2aT[n2 * 256 + k2] = __float2bfloat16(slot_dec_W[idx]);
        }
    } else {
        // ---- doc path: one block per batch row b, pure fp32 ----
        const int b  = blk - 256;
        const int wv = t >> 6;          // wave id: token-subset
        const int ln = t & 63;          // lane: 4 consecutive cols (float4)
        const int* toks = token_ids + b * SEQ;

        float4 acc = make_float4(0.f, 0.f, 0.f, 0.f);
        #pragma unroll 8
        for (int i = 0; i < 32; ++i) {
            const long tok = toks[wv * 32 + i];
            const float4 v = *(const float4*)(emb_table + tok * EMB + ln * 4);
            acc.x += v.x; acc.y += v.y; acc.z += v.z; acc.w += v.w;
        }
        *(float4*)(&red[wv][ln * 4]) = acc;
        __syncthreads();

        sent[t] = (red[0][t] + red[1][t] + red[2][t] + red[3][t]) * (1.0f / 128.0f);
        __syncthreads();

        float a = doc_enc_b[t];
        #pragma unroll 16
        for (int k = 0; k < EMB; ++k)
            a = fmaf(sent[k], doc_enc_W[k * ENC + t], a);
        senc[t] = fmaxf(a, 0.f);
        __syncthreads();

        if (t < NIN) {
            float a2 = doc_dec_b[t];
            #pragma unroll 16
            for (int k = 0; k < ENC; ++k)
                a2 = fmaf(senc[k], doc_dec_W[k * NIN + t], a2);
            out_intent[b * NIN + t] = a2;         // fp32 store
        }
    }
}

// ---------------------------------------------------------------------------
// Kernel 2: fused word_enc + slots GEMMs. 256 blocks x 256 thr (4 waves).
// Block handles 32 consecutive word rows. fp32 gather -> bf16 fragments.
// Stage 1: word_enc[32x256] = relu(emb @ W1 + b1)  (wave owns 64 N-cols)
// Stage 2: slots[32x128]    = word_enc @ W2a + b2 + onehot-row (wave owns 32)
// MFMA 16x16x32 bf16; layouts: A[m=lane&15][k=quad*8+j],
// B[k=quad*8+j][n=lane&15], D[row=quad*4+r][col=lane&15].
// ---------------------------------------------------------------------------
__global__ __launch_bounds__(256) void slots_kernel(
    const int*   __restrict__ token_ids,
    const int*   __restrict__ all_intents,
    const float* __restrict__ emb_table,
    const __hip_bfloat16* __restrict__ W1T,   // [n][k] 256x256 bf16
    const float* __restrict__ b1,             // slot_enc_b fp32
    const __hip_bfloat16* __restrict__ W2aT,  // [n][k] 128x256 bf16
    const float* __restrict__ W2,             // slot_dec_W full [320][128] fp32
    const float* __restrict__ b2,             // slot_dec_b fp32
    float* __restrict__ out_slots)            // fp32 [8192][128]
{
    // 264-elem row stride: breaks 16-way LDS bank aliasing, keeps 16B align.
    __shared__ __align__(16) __hip_bfloat16 lds_we[32 * 264];

    const int blk  = blockIdx.x;       // 256 blocks
    const int row0 = blk * 32;         // first global word row of this block
    const int wave = threadIdx.x >> 6;
    const int lane = threadIdx.x & 63;
    const int l16  = lane & 15;
    const int quad = lane >> 4;

    // ---------------- stage 1 ----------------
    f32x4 acc[2][4];
    #pragma unroll
    for (int mt = 0; mt < 2; ++mt)
        #pragma unroll
        for (int nt = 0; nt < 4; ++nt)
            acc[mt][nt] = (f32x4){0.f, 0.f, 0.f, 0.f};

    const long tok0 = token_ids[row0 + l16];
    const long tok1 = token_ids[row0 + 16 + l16];
    const float* arow0 = emb_table + tok0 * EMB + quad * 8;
    const float* arow1 = emb_table + tok1 * EMB + quad * 8;
    const int nbase1 = wave * 64;

    #pragma unroll
    for (int ks = 0; ks < 8; ++ks) {
        const bf16x8 a0 = cvt8(*(const float4*)(arow0 + ks * 32),
                               *(const float4*)(arow0 + ks * 32 + 4));
        const bf16x8 a1 = cvt8(*(const float4*)(arow1 + ks * 32),
                               *(const float4*)(arow1 + ks * 32 + 4));
        #pragma unroll
        for (int nt = 0; nt < 4; ++nt) {
            const bf16x8 bf =
                *(const bf16x8*)(W1T + (nbase1 + nt * 16 + l16) * 256 + ks * 32 + quad * 8);
            acc[0][nt] = __builtin_amdgcn_mfma_f32_16x16x32_bf16(a0, bf, acc[0][nt], 0, 0, 0);
            acc[1][nt] = __builtin_amdgcn_mfma_f32_16x16x32_bf16(a1, bf, acc[1][nt], 0, 0, 0);
        }
    }

    // relu + bias -> bf16 tile in LDS
    #pragma unroll
    for (int nt = 0; nt < 4; ++nt) {
        const int col = nbase1 + nt * 16 + l16;
        const float bias = b1[col];
        #pragma unroll
        for (int mt = 0; mt < 2; ++mt) {
            #pragma unroll
            for (int r = 0; r < 4; ++r) {
                const int row = mt * 16 + quad * 4 + r;
                lds_we[row * 264 + col] =
                    __float2bfloat16(fmaxf(acc[mt][nt][r] + bias, 0.f));
            }
        }
    }
    __syncthreads();

    // ---------------- stage 2 ----------------
    f32x4 acc2[2][2];
    #pragma unroll
    for (int mt = 0; mt < 2; ++mt)
        #pragma unroll
        for (int nt = 0; nt < 2; ++nt)
            acc2[mt][nt] = (f32x4){0.f, 0.f, 0.f, 0.f};

    const int nbase2 = wave * 32;
    #pragma unroll
    for (int ks = 0; ks < 8; ++ks) {
        const bf16x8 a0 = *(const bf16x8*)(lds_we + l16 * 264 + ks * 32 + quad * 8);
        const bf16x8 a1 = *(const bf16x8*)(lds_we + (16 + l16) * 264 + ks * 32 + quad * 8);
        #pragma unroll
        for (int nt = 0; nt < 2; ++nt) {
            const bf16x8 bf =
                *(const bf16x8*)(W2aT + (nbase2 + nt * 16 + l16) * 256 + ks * 32 + quad * 8);
            acc2[0][nt] = __builtin_amdgcn_mfma_f32_16x16x32_bf16(a0, bf, acc2[0][nt], 0, 0, 0);
            acc2[1][nt] = __builtin_amdgcn_mfma_f32_16x16x32_bf16(a1, bf, acc2[1][nt], 0, 0, 0);
        }
    }

    // epilogue: + slot_dec_b + slot_dec_W[256 + intent[b]] row (fp32), store fp32
    const int bidx   = row0 >> 7;               // 128 words per batch
    const int intent = all_intents[bidx];
    const float* hotrow = W2 + (256 + intent) * NSL;

    #pragma unroll
    for (int nt = 0; nt < 2; ++nt) {
        const int col = nbase2 + nt * 16 + l16;
        const float add = b2[col] + hotrow[col];
        #pragma unroll
        for (int mt = 0; mt < 2; ++mt) {
            #pragma unroll
            for (int r = 0; r < 4; ++r) {
                const int row = mt * 16 + quad * 4 + r;
                out_slots[(long)(row0 + row) * NSL + col] = acc2[mt][nt][r] + add;
            }
        }
    }
}

// ---------------------------------------------------------------------------
extern "C" void kernel_launch(void* const* d_in, const int* in_sizes, int n_in,
                              void* d_out, int out_size, void* d_ws, size_t ws_size,
                              hipStream_t stream) {
    const int*   token_ids   = (const int*)d_in[0];
    const int*   all_intents = (const int*)d_in[1];
    const float* emb_table   = (const float*)d_in[2];
    const float* doc_enc_W   = (const float*)d_in[3];
    const float* doc_enc_b   = (const float*)d_in[4];
    const float* slot_enc_W  = (const float*)d_in[5];
    const float* slot_enc_b  = (const float*)d_in[6];
    const float* doc_dec_W   = (const float*)d_in[7];
    const float* doc_dec_b   = (const float*)d_in[8];
    const float* slot_dec_W  = (const float*)d_in[9];
    const float* slot_dec_b  = (const float*)d_in[10];

    float*          out  = (float*)d_out;               // fp32 output buffer
    __hip_bfloat16* W1T  = (__hip_bfloat16*)d_ws;       // 64K elems (128 KB)
    __hip_bfloat16* W2aT = W1T + 256 * 256;             // 32K elems (64 KB)

    prep_doc_kernel<<<320, 256, 0, stream>>>(
        token_ids, emb_table, doc_enc_W, doc_enc_b, doc_dec_W, doc_dec_b,
        slot_enc_W, slot_dec_W, W1T, W2aT, out);

    slots_kernel<<<256, 256, 0, stream>>>(
        token_ids, all_intents, emb_table, W1T, slot_enc_b,
        W2aT, slot_dec_W, slot_dec_b, out + BATCH * NIN);
}

// Round 4
// 171.248 us; speedup vs baseline: 1.0592x; 1.0592x over previous
//
#include <hip/hip_runtime.h>
#include <hip/hip_bf16.h>

// MFMA fragment types (cdna_hip_programming.md §3)
typedef __attribute__((ext_vector_type(8))) short bf16x8;
typedef __attribute__((ext_vector_type(4))) float f32x4;

#define BATCH 64
#define SEQ   128
#define EMB   256
#define ENC   256
#define NIN   64
#define NSL   128

static __device__ __forceinline__ bf16x8 cvt8(const float4 lo, const float4 hi) {
    union { bf16x8 v; __hip_bfloat16 h[8]; } u;
    u.h[0] = __float2bfloat16(lo.x); u.h[1] = __float2bfloat16(lo.y);
    u.h[2] = __float2bfloat16(lo.z); u.h[3] = __float2bfloat16(lo.w);
    u.h[4] = __float2bfloat16(hi.x); u.h[5] = __float2bfloat16(hi.y);
    u.h[6] = __float2bfloat16(hi.z); u.h[7] = __float2bfloat16(hi.w);
    return u.v;
}

// Build a B-fragment (B[k=quad*8+j][n], j=0..7) directly from a row-major
// fp32 weight W[k][n] with leading dim ldn. 8 k-strided scalar loads, each
// wave-inst coalesces into 4x64B L2-hit segments (16 consecutive n per quad).
static __device__ __forceinline__ bf16x8 load_bT(const float* __restrict__ W,
                                                 int ldn, int k0, int n) {
    union { bf16x8 v; __hip_bfloat16 h[8]; } u;
    #pragma unroll
    for (int j = 0; j < 8; ++j)
        u.h[j] = __float2bfloat16(W[(long)(k0 + j) * ldn + n]);
    return u.v;
}

// ---------------------------------------------------------------------------
// ONE fused kernel, no workspace.
//   blocks 0..255  : slots path, 32 word-rows per block, 4 waves.
//     Stage 1: word_enc[32x256] = relu(emb @ W1 + b1)   (wave owns 64 N-cols)
//     Stage 2: slots[32x128]    = word_enc @ W2a + b2 + onehot-row (wave: 32)
//     MFMA 16x16x32 bf16; A[m=lane&15][k=quad*8+j], B[k=quad*8+j][n=lane&15],
//     D[row=quad*4+r][col=lane&15]. B-fragments built directly from fp32
//     weights (L2-resident), fp32 A gathered + cvt in-register.
//   blocks 256..319: doc path, one block per batch row, pure fp32 VALU.
// ---------------------------------------------------------------------------
__global__ __launch_bounds__(256) void fused_kernel(
    const int*   __restrict__ token_ids,
    const int*   __restrict__ all_intents,
    const float* __restrict__ emb_table,
    const float* __restrict__ doc_enc_W,
    const float* __restrict__ doc_enc_b,
    const float* __restrict__ slot_enc_W,   // [256][256]
    const float* __restrict__ slot_enc_b,
    const float* __restrict__ doc_dec_W,
    const float* __restrict__ doc_dec_b,
    const float* __restrict__ slot_dec_W,   // [320][128]
    const float* __restrict__ slot_dec_b,
    float* __restrict__ out_intent,         // fp32 [64][64]
    float* __restrict__ out_slots)          // fp32 [8192][128]
{
    // 264-elem row stride breaks the 16-way LDS bank aliasing on K-major reads.
    __shared__ __align__(16) __hip_bfloat16 lds_we[32 * 264];   // 16.5 KB
    __shared__ __align__(16) float red[4][256];                 // doc path
    __shared__ float sent[ENC];
    __shared__ float senc[ENC];

    const int blk = blockIdx.x;

    if (blk < 256) {
        // ================= slots path =================
        const int row0 = blk * 32;
        const int wave = threadIdx.x >> 6;
        const int lane = threadIdx.x & 63;
        const int l16  = lane & 15;
        const int quad = lane >> 4;

        // ---------------- stage 1 ----------------
        f32x4 acc[2][4];
        #pragma unroll
        for (int mt = 0; mt < 2; ++mt)
            #pragma unroll
            for (int nt = 0; nt < 4; ++nt)
                acc[mt][nt] = (f32x4){0.f, 0.f, 0.f, 0.f};

        const long tok0 = token_ids[row0 + l16];
        const long tok1 = token_ids[row0 + 16 + l16];
        const float* arow0 = emb_table + tok0 * EMB + quad * 8;
        const float* arow1 = emb_table + tok1 * EMB + quad * 8;
        const int nbase1 = wave * 64;

        #pragma unroll
        for (int ks = 0; ks < 8; ++ks) {
            const bf16x8 a0 = cvt8(*(const float4*)(arow0 + ks * 32),
                                   *(const float4*)(arow0 + ks * 32 + 4));
            const bf16x8 a1 = cvt8(*(const float4*)(arow1 + ks * 32),
                                   *(const float4*)(arow1 + ks * 32 + 4));
            const int k0 = ks * 32 + quad * 8;
            #pragma unroll
            for (int nt = 0; nt < 4; ++nt) {
                const bf16x8 bf = load_bT(slot_enc_W, ENC, k0, nbase1 + nt * 16 + l16);
                acc[0][nt] = __builtin_amdgcn_mfma_f32_16x16x32_bf16(a0, bf, acc[0][nt], 0, 0, 0);
                acc[1][nt] = __builtin_amdgcn_mfma_f32_16x16x32_bf16(a1, bf, acc[1][nt], 0, 0, 0);
            }
        }

        // relu + bias -> bf16 tile in LDS
        #pragma unroll
        for (int nt = 0; nt < 4; ++nt) {
            const int col = nbase1 + nt * 16 + l16;
            const float bias = slot_enc_b[col];
            #pragma unroll
            for (int mt = 0; mt < 2; ++mt) {
                #pragma unroll
                for (int r = 0; r < 4; ++r) {
                    const int row = mt * 16 + quad * 4 + r;
                    lds_we[row * 264 + col] =
                        __float2bfloat16(fmaxf(acc[mt][nt][r] + bias, 0.f));
                }
            }
        }
        __syncthreads();

        // ---------------- stage 2 ----------------
        f32x4 acc2[2][2];
        #pragma unroll
        for (int mt = 0; mt < 2; ++mt)
            #pragma unroll
            for (int nt = 0; nt < 2; ++nt)
                acc2[mt][nt] = (f32x4){0.f, 0.f, 0.f, 0.f};

        const int nbase2 = wave * 32;
        #pragma unroll
        for (int ks = 0; ks < 8; ++ks) {
            const bf16x8 a0 = *(const bf16x8*)(lds_we + l16 * 264 + ks * 32 + quad * 8);
            const bf16x8 a1 = *(const bf16x8*)(lds_we + (16 + l16) * 264 + ks * 32 + quad * 8);
            const int k0 = ks * 32 + quad * 8;
            #pragma unroll
            for (int nt = 0; nt < 2; ++nt) {
                const bf16x8 bf = load_bT(slot_dec_W, NSL, k0, nbase2 + nt * 16 + l16);
                acc2[0][nt] = __builtin_amdgcn_mfma_f32_16x16x32_bf16(a0, bf, acc2[0][nt], 0, 0, 0);
                acc2[1][nt] = __builtin_amdgcn_mfma_f32_16x16x32_bf16(a1, bf, acc2[1][nt], 0, 0, 0);
            }
        }

        // epilogue: + slot_dec_b + slot_dec_W[256 + intent[b]] row, fp32 store
        const int intent = all_intents[row0 >> 7];
        const float* hotrow = slot_dec_W + (long)(256 + intent) * NSL;

        #pragma unroll
        for (int nt = 0; nt < 2; ++nt) {
            const int col = nbase2 + nt * 16 + l16;
            const float add = slot_dec_b[col] + hotrow[col];
            #pragma unroll
            for (int mt = 0; mt < 2; ++mt) {
                #pragma unroll
                for (int r = 0; r < 4; ++r) {
                    const int row = mt * 16 + quad * 4 + r;
                    out_slots[(long)(row0 + row) * NSL + col] = acc2[mt][nt][r] + add;
                }
            }
        }
    } else {
        // ================= doc path: one block per batch row =================
        const int b  = blk - 256;
        const int t  = threadIdx.x;
        const int wv = t >> 6;          // wave id: token-subset
        const int ln = t & 63;          // lane: 4 consecutive cols (float4)
        const int* toks = token_ids + b * SEQ;

        float4 accv = make_float4(0.f, 0.f, 0.f, 0.f);
        #pragma unroll 8
        for (int i = 0; i < 32; ++i) {
            const long tok = toks[wv * 32 + i];
            const float4 v = *(const float4*)(emb_table + tok * EMB + ln * 4);
            accv.x += v.x; accv.y += v.y; accv.z += v.z; accv.w += v.w;
        }
        *(float4*)(&red[wv][ln * 4]) = accv;
        __syncthreads();

        sent[t] = (red[0][t] + red[1][t] + red[2][t] + red[3][t]) * (1.0f / 128.0f);
        __syncthreads();

        float a = doc_enc_b[t];
        #pragma unroll 16
        for (int k = 0; k < EMB; ++k)
            a = fmaf(sent[k], doc_enc_W[k * ENC + t], a);
        senc[t] = fmaxf(a, 0.f);
        __syncthreads();

        if (t < NIN) {
            float a2 = doc_dec_b[t];
            #pragma unroll 16
            for (int k = 0; k < ENC; ++k)
                a2 = fmaf(senc[k], doc_dec_W[k * NIN + t], a2);
            out_intent[b * NIN + t] = a2;
        }
    }
}

// ---------------------------------------------------------------------------
extern "C" void kernel_launch(void* const* d_in, const int* in_sizes, int n_in,
                              void* d_out, int out_size, void* d_ws, size_t ws_size,
                              hipStream_t stream) {
    const int*   token_ids   = (const int*)d_in[0];
    const int*   all_intents = (const int*)d_in[1];
    const float* emb_table   = (const float*)d_in[2];
    const float* doc_enc_W   = (const float*)d_in[3];
    const float* doc_enc_b   = (const float*)d_in[4];
    const float* slot_enc_W  = (const float*)d_in[5];
    const float* slot_enc_b  = (const float*)d_in[6];
    const float* doc_dec_W   = (const float*)d_in[7];
    const float* doc_dec_b   = (const float*)d_in[8];
    const float* slot_dec_W  = (const float*)d_in[9];
    const float* slot_dec_b  = (const float*)d_in[10];

    float* out = (float*)d_out;     // [0,4096): intents fp32; rest: slots fp32

    fused_kernel<<<320, 256, 0, stream>>>(
        token_ids, all_intents, emb_table, doc_enc_W, doc_enc_b,
        slot_enc_W, slot_enc_b, doc_dec_W, doc_dec_b, slot_dec_W, slot_dec_b,
        out, out + BATCH * NIN);
}